// Round 8
// baseline (173.413 us; speedup 1.0000x reference)
//
#include <hip/hip_runtime.h>
#include <stdint.h>

// CRF loss: S=32768, L=512. Chunked forward algorithm, exp-domain, fp8 MFMA.
// CH=8 -> 4096 fwd + 4095 bwd chunks; each WG owns TWO independent 16-col
// groups (A: b*32+cl, B: b*32+16+cl) sharing register-resident E ->
// 128 fwd + 128 bwd WGs = 256 WGs (1/CU, forced: E-in-regs ~228 regs/wave).
// Two groups double independent work per barrier interval and halve barrier
// count (8 steps vs 16) -> attacks the latency-bound 8100cyc/step of r3.
// Exact 2-barrier renorm (r7 stale-scale regressed speed AND accuracy: 96us,
// absmax 2048 -> reverted). r6 proved CH=8 numerics exact (absmax 0.0).
// Per step/group: C[512x16] = E' x P (v_mfma 16x16x32 fp8), *exp(feat),
// column max renorm -> fp8 P' in LDS (B-frag layout).
// m accumulates log(M) - ln448 - ln2 (-ln2 compensates E'=2E).
// Tail fused: pair tickets (fwd b + bwd b own chunks 32b+1..32b+32) + final
// ticket last-WG reduction. 2 kernels total.

#define S_LEN 32768
#define L 512
#define CH 8
#define NCF 4096
#define WGF 128
#define WGB 128
#define NWG 256
#define LN448 6.104793232f
#define LN2   0.6931471806f

// ws layout (bytes), ~8.6 MB
#define OFF_EAF  0                       // 256 KB A-frag fp8 E'  (fwd)
#define OFF_EAB  (256*1024)              // 256 KB A-frag fp8 E'^T (bwd)
#define OFF_G    (512*1024)              // 4096*512 bf16 (4 MB)
#define OFF_H    (OFF_G + NCF*L*2)       // 4096*512 bf16 (4 MB, row 0 unused)
#define OFF_LSE  (OFF_H + NCF*L*2)       // [c]=lse(h+g), [NCF+c]=lse(h), [2NCF]=lse(g_last)
#define OFF_PART (OFF_LSE + (2*NCF+4)*4) // 256 f32 gold partials
#define OFF_PTKT (OFF_PART + NWG*4)      // 128 u32 pair tickets
#define OFF_FTKT (OFF_PTKT + WGF*4)      // 1 u32 final ticket

typedef float v4f __attribute__((ext_vector_type(4)));

__device__ __forceinline__ float b2f(unsigned short u){
  return __uint_as_float(((unsigned)u) << 16);
}
__device__ __forceinline__ unsigned short f2b(float x){
  unsigned u = __float_as_uint(x);
  return (unsigned short)((u + 0x7fffu + ((u >> 16) & 1u)) >> 16);
}
__device__ __forceinline__ unsigned char to_fp8(float v){
  int u = __builtin_amdgcn_cvt_pk_fp8_f32(v, v, 0, false);
  return (unsigned char)(u & 0xff);
}

// ---------- prep: A-fragment-swizzled fp8 E'/E'^T + ticket zeroing ----------
extern "C" __global__ void crf_prep(const float* __restrict__ T,
                                    unsigned char* __restrict__ EAf,
                                    unsigned char* __restrict__ EAb,
                                    unsigned int* __restrict__ ptkt,
                                    unsigned int* __restrict__ ftkt){
  int tid = blockIdx.x*512 + threadIdx.x;        // 0..262143
  if (tid < WGF + 1) { if (tid < WGF) ptkt[tid] = 0u; else *ftkt = 0u; }
  int r    = tid & 7;
  int lane = (tid >> 3) & 63;
  int kt   = (tid >> 9) & 15;
  int mtw  = tid >> 13;                          // w*4+mt, 0..31
  int j = (mtw >> 2)*64 + (mtw & 3)*16 + (lane & 15);
  int i = kt*32 + ((lane >> 4) << 3) + r;
  EAf[tid] = to_fp8(2.0f * __expf(T[j*L + i]));  // E'[j][i]
  EAb[tid] = to_fp8(2.0f * __expf(T[i*L + j]));  // E'^T[j][i]
}

// ---------- block sum over 512 threads ----------
__device__ __forceinline__ float blockSum(float v, float* sred){
  #pragma unroll
  for (int off = 32; off >= 1; off >>= 1) v += __shfl_xor(v, off);
  int wid = threadIdx.x >> 6, lane = threadIdx.x & 63;
  if (lane == 0) sred[wid] = v;
  __syncthreads();
  if (threadIdx.x < 8) {
    float t = sred[threadIdx.x];
    t += __shfl_xor(t, 4); t += __shfl_xor(t, 2); t += __shfl_xor(t, 1);
    if (threadIdx.x == 0) sred[15] = t;
  }
  __syncthreads();
  float r = sred[15];
  __syncthreads();
  return r;
}

// ---------- main kernel ----------
extern "C" __global__ __launch_bounds__(512, 2)
void crf_chunks(const float* __restrict__ logit,
                const unsigned char* __restrict__ EAf,
                const unsigned char* __restrict__ EAb,
                unsigned short* __restrict__ G, unsigned short* __restrict__ H,
                const int* __restrict__ labels, const float* __restrict__ T,
                float* __restrict__ part, float* __restrict__ lsebuf,
                unsigned int* __restrict__ ptkt, unsigned int* __restrict__ ftkt,
                float* __restrict__ out){
  // P in MFMA-B-fragment order: byte(n=col,k=row) =
  //   (k>>5)*512 + (((k>>3)&3)*16 + n)*8 + (k&7)
  __shared__ __align__(16) unsigned char PlA[2][8192];
  __shared__ __align__(16) unsigned char PlB[2][8192];
  __shared__ __align__(16) float sPartA[16][8];
  __shared__ __align__(16) float sPartB[16][8];
  __shared__ float sred[16];
  __shared__ unsigned sOld, sOld2;

  const int tid  = threadIdx.x;
  const int w    = tid >> 6;
  const int lane = tid & 63;
  const int quad = lane >> 4;
  const int cl   = lane & 15;                    // MFMA column within group
  const bool fwd = (blockIdx.x < WGF);
  const int  b   = fwd ? blockIdx.x : (blockIdx.x - WGF);
  const int  cgA = fwd ? (b*32 + cl)      : (1 + b*32 + cl);
  const int  cgB = fwd ? (b*32 + 16 + cl) : (1 + b*32 + 16 + cl);
  const int  ccA = min(cgA, NCF-1);
  const int  ccB = min(cgB, NCF-1);
  const bool isc0 = fwd && (cgA == 0);           // only group A can hold chunk 0
  const int  jrow0 = w*64 + quad*4;              // C-layout base row (+mt*16)

  // ---- E fragments in registers (shared by both groups) ----
  const long* EA = (const long*)(fwd ? EAf : EAb);
  long eA[4][16];
  #pragma unroll
  for (int mt = 0; mt < 4; ++mt)
    #pragma unroll
    for (int kt = 0; kt < 16; ++kt)
      eA[mt][kt] = EA[(((w<<2)+mt)<<4 | kt)*64 + lane];

  float vrA[4][4], vrB[4][4];
  float mA = 0.0f, mB = 0.0f;

  // wave-local column max of a vr
  auto wmax = [&](const float (&vr)[4][4])->float{
    float mx = vr[0][0];
    #pragma unroll
    for (int mt = 0; mt < 4; ++mt)
      #pragma unroll
      for (int r = 0; r < 4; ++r) mx = fmaxf(mx, vr[mt][r]);
    mx = fmaxf(mx, __shfl_xor(mx, 16));
    mx = fmaxf(mx, __shfl_xor(mx, 32));
    return mx;
  };
  // cross-wave max from a sPart (after barrier)
  auto max8 = [&](const float (&sP)[16][8])->float{
    float4 pa = *(const float4*)&sP[cl][0];
    float4 pb = *(const float4*)&sP[cl][4];
    return fmaxf(fmaxf(fmaxf(pa.x,pa.y),fmaxf(pa.z,pa.w)),
                 fmaxf(fmaxf(pb.x,pb.y),fmaxf(pb.z,pb.w)));
  };
  // pack vr*sc -> Pl[dst] (B-frag layout)
  auto packg = [&](unsigned char (&Pl)[2][8192], int dst,
                   const float (&vr)[4][4], float &m, float M){
    float sc = 448.0f / M;
    #pragma unroll
    for (int mt = 0; mt < 4; ++mt) {
      int u = __builtin_amdgcn_cvt_pk_fp8_f32(vr[mt][0]*sc, vr[mt][1]*sc, 0, false);
      u     = __builtin_amdgcn_cvt_pk_fp8_f32(vr[mt][2]*sc, vr[mt][3]*sc, u, true);
      int r0 = jrow0 + mt*16;
      *(int*)&Pl[dst][(r0 >> 5)*512 + ((((r0 >> 3) & 3)*16 + cl) << 3) + (r0 & 7)] = u;
    }
    m += __logf(M) - LN448;
  };
  // one group's MFMA + epilogue for step k (k <= CH-2), leaves vr/m updated
  // and wave max in sPart (quad 0)
  auto mfma_ep = [&](int k, const unsigned char (&Pl)[2][8192], int rd,
                     float (&vr)[4][4], float &m, int cgc, bool anchor,
                     float (&sP)[16][8]){
    const int t = fwd ? (cgc*CH + k) : (cgc*CH + CH - 2 - k);
    const float* lp = logit + (size_t)t*L + jrow0;
    float4 x0 = *(const float4*)(lp);      float4 x1 = *(const float4*)(lp + 16);
    float4 x2 = *(const float4*)(lp + 32); float4 x3 = *(const float4*)(lp + 48);
    v4f acc[4];
    #pragma unroll
    for (int mt = 0; mt < 4; ++mt) acc[mt] = (v4f){0.f,0.f,0.f,0.f};
    #pragma unroll
    for (int kt = 0; kt < 16; ++kt) {
      long bb = *(const long*)&Pl[rd][kt*512 + lane*8];
      #pragma unroll
      for (int mt = 0; mt < 4; ++mt)
        acc[mt] = __builtin_amdgcn_mfma_f32_16x16x32_fp8_fp8(eA[mt][kt], bb, acc[mt], 0, 0, 0);
    }
    m -= LN2;                                    // compensate E' = 2E
    float4 xs[4] = {x0, x1, x2, x3};
    #pragma unroll
    for (int mt = 0; mt < 4; ++mt) {
      float f0 = __expf(xs[mt].x), f1 = __expf(xs[mt].y);
      float f2 = __expf(xs[mt].z), f3 = __expf(xs[mt].w);
      vr[mt][0] = acc[mt][0]*f0; vr[mt][1] = acc[mt][1]*f1;
      vr[mt][2] = acc[mt][2]*f2; vr[mt][3] = acc[mt][3]*f3;
      if (anchor) { vr[mt][0] = f0; vr[mt][1] = f1; vr[mt][2] = f2; vr[mt][3] = f3; }
    }
    if (anchor) m = 0.0f;
    float mx = wmax(vr);
    if (quad == 0) sP[cl][w] = mx;
  };

  // ---- seed both groups -> Pl*[0] ----
  if (fwd) {
    #pragma unroll
    for (int mt = 0; mt < 4; ++mt)
      #pragma unroll
      for (int r = 0; r < 4; ++r) { vrA[mt][r] = 1.0f; vrB[mt][r] = 1.0f; }
  } else {
    const float* lpA = logit + (size_t)(ccA*CH + CH - 1)*L + jrow0;
    const float* lpB = logit + (size_t)(ccB*CH + CH - 1)*L + jrow0;
    #pragma unroll
    for (int mt = 0; mt < 4; ++mt) {
      float4 xa = *(const float4*)(lpA + mt*16);
      float4 xb = *(const float4*)(lpB + mt*16);
      vrA[mt][0] = __expf(xa.x); vrA[mt][1] = __expf(xa.y);
      vrA[mt][2] = __expf(xa.z); vrA[mt][3] = __expf(xa.w);
      vrB[mt][0] = __expf(xb.x); vrB[mt][1] = __expf(xb.y);
      vrB[mt][2] = __expf(xb.z); vrB[mt][3] = __expf(xb.w);
    }
  }
  {
    float ma = wmax(vrA), mb = wmax(vrB);
    if (quad == 0) { sPartA[cl][w] = ma; sPartB[cl][w] = mb; }
    __syncthreads();
    packg(PlA, 0, vrA, mA, max8(sPartA));
    packg(PlB, 0, vrB, mB, max8(sPartB));
    __syncthreads();
  }

  // ---- steps 0..CH-2: two independent groups per barrier interval ----
  #pragma unroll
  for (int k = 0; k <= CH-2; ++k) {
    const int rd = k & 1, wr = rd ^ 1;
    mfma_ep(k, PlA, rd, vrA, mA, ccA, isc0 && (k == 0), sPartA);
    mfma_ep(k, PlB, rd, vrB, mB, ccB, false, sPartB);
    __syncthreads();
    packg(PlA, wr, vrA, mA, max8(sPartA));
    packg(PlB, wr, vrB, mB, max8(sPartB));
    __syncthreads();
  }

  // ---- last step (k = CH-1): pure matvec (+feat only for fwd), store G/H ----
  {
    const int k = CH-1, rd = k & 1;
    float4 xa0, xa1, xa2, xa3, xb0, xb1, xb2, xb3;
    if (fwd) {
      const float* lpA = logit + (size_t)(ccA*CH + k)*L + jrow0;
      const float* lpB = logit + (size_t)(ccB*CH + k)*L + jrow0;
      xa0 = *(const float4*)(lpA);      xa1 = *(const float4*)(lpA + 16);
      xa2 = *(const float4*)(lpA + 32); xa3 = *(const float4*)(lpA + 48);
      xb0 = *(const float4*)(lpB);      xb1 = *(const float4*)(lpB + 16);
      xb2 = *(const float4*)(lpB + 32); xb3 = *(const float4*)(lpB + 48);
    }
    v4f accA[4], accB[4];
    #pragma unroll
    for (int mt = 0; mt < 4; ++mt) { accA[mt] = (v4f){0.f,0.f,0.f,0.f}; accB[mt] = (v4f){0.f,0.f,0.f,0.f}; }
    #pragma unroll
    for (int kt = 0; kt < 16; ++kt) {
      long ba = *(const long*)&PlA[rd][kt*512 + lane*8];
      long bb = *(const long*)&PlB[rd][kt*512 + lane*8];
      #pragma unroll
      for (int mt = 0; mt < 4; ++mt) {
        accA[mt] = __builtin_amdgcn_mfma_f32_16x16x32_fp8_fp8(eA[mt][kt], ba, accA[mt], 0, 0, 0);
        accB[mt] = __builtin_amdgcn_mfma_f32_16x16x32_fp8_fp8(eA[mt][kt], bb, accB[mt], 0, 0, 0);
      }
    }
    mA -= LN2; mB -= LN2;
    if (fwd) {
      float4 xsa[4] = {xa0, xa1, xa2, xa3};
      float4 xsb[4] = {xb0, xb1, xb2, xb3};
      #pragma unroll
      for (int mt = 0; mt < 4; ++mt) {
        vrA[mt][0] = accA[mt][0]*__expf(xsa[mt].x); vrA[mt][1] = accA[mt][1]*__expf(xsa[mt].y);
        vrA[mt][2] = accA[mt][2]*__expf(xsa[mt].z); vrA[mt][3] = accA[mt][3]*__expf(xsa[mt].w);
        vrB[mt][0] = accB[mt][0]*__expf(xsb[mt].x); vrB[mt][1] = accB[mt][1]*__expf(xsb[mt].y);
        vrB[mt][2] = accB[mt][2]*__expf(xsb[mt].z); vrB[mt][3] = accB[mt][3]*__expf(xsb[mt].w);
      }
    } else {
      #pragma unroll
      for (int mt = 0; mt < 4; ++mt)
        #pragma unroll
        for (int r = 0; r < 4; ++r) { vrA[mt][r] = accA[mt][r]; vrB[mt][r] = accB[mt][r]; }
    }
    unsigned short* base = fwd ? G : H;
    if (cgA <= NCF-1) {
      unsigned short* dst = base + (size_t)cgA*L + jrow0;
      #pragma unroll
      for (int mt = 0; mt < 4; ++mt) {
        ushort4 o;
        o.x = f2b(__logf(vrA[mt][0]) + mA); o.y = f2b(__logf(vrA[mt][1]) + mA);
        o.z = f2b(__logf(vrA[mt][2]) + mA); o.w = f2b(__logf(vrA[mt][3]) + mA);
        *(ushort4*)(dst + mt*16) = o;
      }
    }
    if (cgB <= NCF-1) {
      unsigned short* dst = base + (size_t)cgB*L + jrow0;
      #pragma unroll
      for (int mt = 0; mt < 4; ++mt) {
        ushort4 o;
        o.x = f2b(__logf(vrB[mt][0]) + mB); o.y = f2b(__logf(vrB[mt][1]) + mB);
        o.z = f2b(__logf(vrB[mt][2]) + mB); o.w = f2b(__logf(vrB[mt][3]) + mB);
        *(ushort4*)(dst + mt*16) = o;
      }
    }
  }

  // ---- gold partial: 128 timesteps per WG ----
  {
    float gv = 0.f;
    if (tid < 128) {
      int t = blockIdx.x*128 + tid;
      int yt = labels[t];
      gv = logit[(size_t)t*L + yt];
      if (t > 0) gv += T[yt*L + labels[t-1]];
    }
    float s = blockSum(gv, sred);
    if (tid == 0) part[blockIdx.x] = s;
  }

  // ---- pair rendezvous: second arriver does lse for chunks 32b+1..32b+32 ----
  __syncthreads();
  if (tid == 0) { __threadfence(); sOld = atomicAdd(&ptkt[b], 1u); }
  __syncthreads();
  if (sOld == 1u) {
    __threadfence();
    #pragma unroll
    for (int q = 0; q < 4; ++q) {
      int idx = w*4 + q;                         // 0..31
      int c = b*32 + 1 + idx;                    // 1..4096
      if (c <= NCF-1) {
        const ushort4* hp = (const ushort4*)(H + (size_t)c*L + lane*8);
        const ushort4* gp = (const ushort4*)(G + (size_t)(c-1)*L + lane*8);
        ushort4 h0 = hp[0], h1 = hp[1], g0 = gp[0], g1 = gp[1];
        float hh[8] = {b2f(h0.x),b2f(h0.y),b2f(h0.z),b2f(h0.w),
                       b2f(h1.x),b2f(h1.y),b2f(h1.z),b2f(h1.w)};
        float aa[8] = {hh[0]+b2f(g0.x),hh[1]+b2f(g0.y),hh[2]+b2f(g0.z),hh[3]+b2f(g0.w),
                       hh[4]+b2f(g1.x),hh[5]+b2f(g1.y),hh[6]+b2f(g1.z),hh[7]+b2f(g1.w)};
        float Ma = aa[0], Mh = hh[0];
        #pragma unroll
        for (int r = 1; r < 8; ++r) { Ma = fmaxf(Ma, aa[r]); Mh = fmaxf(Mh, hh[r]); }
        #pragma unroll
        for (int off = 1; off <= 32; off <<= 1) {
          Ma = fmaxf(Ma, __shfl_xor(Ma, off));
          Mh = fmaxf(Mh, __shfl_xor(Mh, off));
        }
        float sa = 0.f, sh = 0.f;
        #pragma unroll
        for (int r = 0; r < 8; ++r) { sa += __expf(aa[r]-Ma); sh += __expf(hh[r]-Mh); }
        #pragma unroll
        for (int off = 1; off <= 32; off <<= 1) {
          sa += __shfl_xor(sa, off);
          sh += __shfl_xor(sh, off);
        }
        if (lane == 0) { lsebuf[c] = Ma + __logf(sa); lsebuf[NCF + c] = Mh + __logf(sh); }
      } else {                                   // b==127,idx==31: lse(g_last)
        const ushort4* gp = (const ushort4*)(G + (size_t)(NCF-1)*L + lane*8);
        ushort4 u0 = gp[0], u1 = gp[1];
        float v[8] = {b2f(u0.x),b2f(u0.y),b2f(u0.z),b2f(u0.w),
                      b2f(u1.x),b2f(u1.y),b2f(u1.z),b2f(u1.w)};
        float M = v[0];
        #pragma unroll
        for (int r = 1; r < 8; ++r) M = fmaxf(M, v[r]);
        #pragma unroll
        for (int off = 1; off <= 32; off <<= 1) M = fmaxf(M, __shfl_xor(M, off));
        float s = 0.f;
        #pragma unroll
        for (int r = 0; r < 8; ++r) s += __expf(v[r] - M);
        #pragma unroll
        for (int off = 1; off <= 32; off <<= 1) s += __shfl_xor(s, off);
        if (lane == 0) lsebuf[2*NCF] = M + __logf(s);
      }
    }
  }

  // ---- final ticket: 256th WG reduces everything ----
  __syncthreads();
  if (tid == 0) { __threadfence(); sOld2 = atomicAdd(ftkt, 1u); }
  __syncthreads();
  if (sOld2 == (unsigned)(NWG - 1)) {
    __threadfence();
    float acc = 0.f;
    for (int c = tid; c < NCF; c += 512)
      if (c >= 1) acc += lsebuf[c] - lsebuf[NCF + c];
    if (tid < NWG) acc -= part[tid];
    float s = blockSum(acc, sred);
    if (tid == 0) out[0] = lsebuf[2*NCF] + s;
  }
}

extern "C" void kernel_launch(void* const* d_in, const int* in_sizes, int n_in,
                              void* d_out, int out_size, void* d_ws, size_t ws_size,
                              hipStream_t stream){
  const float* logit = (const float*)d_in[0];
  const int* labels  = (const int*)d_in[1];
  const float* T     = (const float*)d_in[2];
  float* out = (float*)d_out;
  char* ws = (char*)d_ws;
  unsigned char* EAf = (unsigned char*)(ws + OFF_EAF);
  unsigned char* EAb = (unsigned char*)(ws + OFF_EAB);
  unsigned short* G  = (unsigned short*)(ws + OFF_G);
  unsigned short* H  = (unsigned short*)(ws + OFF_H);
  float* lsebuf = (float*)(ws + OFF_LSE);
  float* part   = (float*)(ws + OFF_PART);
  unsigned int* ptkt = (unsigned int*)(ws + OFF_PTKT);
  unsigned int* ftkt = (unsigned int*)(ws + OFF_FTKT);

  crf_prep  <<<512, 512, 0, stream>>>(T, EAf, EAb, ptkt, ftkt);
  crf_chunks<<<NWG, 512, 0, stream>>>(logit, EAf, EAb, G, H, labels, T,
                                      part, lsebuf, ptkt, ftkt, out);
}